// Round 5
// baseline (95.053 us; speedup 1.0000x reference)
//
#include <hip/hip_runtime.h>
#include <hip/hip_fp8.h>
#include <stdint.h>
#include <stddef.h>

#define BATCH 8192
#define DIM   256

#define LN2F 0.6931471805599453f
// operand quantization scales; product = 1000*log2(e) = 1442.6950408889634
// so MFMA accs are directly exp2-domain scores (no dequant in hot loop).
#define SCALE_ZJ 16.0f                 // A side (staged), max |z|*16 ~ 5.6 < 448
#define SCALE_ZI 90.16844005556021f    // B side (regs),  max |z|*90 ~ 32  < 448

typedef int   v8i    __attribute__((ext_vector_type(8)));   // 32B fp8 frag (8 VGPR)
typedef float f32x16 __attribute__((ext_vector_type(16)));  // 32x32 MFMA acc

// ---------- helpers ----------
static __device__ __forceinline__ uint8_t f2fp8(float f) {
  __hip_fp8_e4m3 q(f);                       // OCP e4m3fn, RNE+sat
  return *reinterpret_cast<uint8_t*>(&q);
}

// stage one 32-row x 256B fp8 tile (8 KB): linear LDS dest, source pre-swizzled
// with byte ^= ((row&7)<<4) so the ds_read_b128 fragment reads spread banks
// (rule 21: same involution on source and read, LDS dest stays linear).
static __device__ __forceinline__ void stage8(const uint8_t* __restrict__ src,
                                              uint8_t* dst, int tid) {
  const int lane = tid & 63;
  const int w    = tid >> 6;
#pragma unroll
  for (int c = 0; c < 2; ++c) {
    const int L  = (c * 4 + w) * 1024 + lane * 16;   // linear byte in tile
    const int Ls = L ^ (((L >> 8) & 7) << 4);        // swizzled source byte
    __builtin_amdgcn_global_load_lds(
        (const __attribute__((address_space(1))) void*)(src + Ls),
        (__attribute__((address_space(3))) void*)(dst + (c * 4 + w) * 1024),
        16, 0, 0);
  }
}

// ---------- pass 1: normalize, exact fp32 positives, fp8 quantize ----------
__global__ __launch_bounds__(256) void prep_kernel(
    const float* __restrict__ p1, const float* __restrict__ p2,
    uint8_t* __restrict__ Zi8, uint8_t* __restrict__ Zj8,
    float* __restrict__ pos) {
  const int lane = threadIdx.x & 63;
  const int w    = threadIdx.x >> 6;
  const int row  = blockIdx.x * 4 + w;   // one wave per row

  const float4 x1 = ((const float4*)p1)[row * 64 + lane];
  const float4 x2 = ((const float4*)p2)[row * 64 + lane];
  float ss1 = x1.x * x1.x + x1.y * x1.y + x1.z * x1.z + x1.w * x1.w;
  float ss2 = x2.x * x2.x + x2.y * x2.y + x2.z * x2.z + x2.w * x2.w;
  float d   = x1.x * x2.x + x1.y * x2.y + x1.z * x2.z + x1.w * x2.w;
#pragma unroll
  for (int m = 1; m < 64; m <<= 1) {
    ss1 += __shfl_xor(ss1, m);
    ss2 += __shfl_xor(ss2, m);
    d   += __shfl_xor(d, m);
  }
  const float n1 = fmaxf(sqrtf(ss1), 1e-12f);
  const float n2 = fmaxf(sqrtf(ss2), 1e-12f);
  if (lane == 0) pos[row] = d / (n1 * n2);          // exact fp32 diagonal

  const float sI = SCALE_ZI / n1;
  const float sJ = SCALE_ZJ / n2;
  uchar4 u1, u2;
  u1.x = f2fp8(x1.x * sI); u1.y = f2fp8(x1.y * sI);
  u1.z = f2fp8(x1.z * sI); u1.w = f2fp8(x1.w * sI);
  u2.x = f2fp8(x2.x * sJ); u2.y = f2fp8(x2.y * sJ);
  u2.z = f2fp8(x2.z * sJ); u2.w = f2fp8(x2.w * sJ);
  ((uchar4*)Zi8)[row * 64 + lane] = u1;
  ((uchar4*)Zj8)[row * 64 + lane] = u2;
}

// ---------- online lse update for one 16-score acc block ----------
static __device__ __forceinline__ void lse_update(const f32x16& acc,
                                                  float& m, float& l) {
  float mx[8];
#pragma unroll
  for (int r = 0; r < 8; ++r) mx[r] = fmaxf(acc[r], acc[r + 8]);
#pragma unroll
  for (int r = 0; r < 4; ++r) mx[r] = fmaxf(mx[r], mx[r + 4]);
  const float tmax = fmaxf(fmaxf(mx[0], mx[1]), fmaxf(mx[2], mx[3]));
  const float mn = fmaxf(m, tmax);
  float s0 = 0.f, s1 = 0.f, s2 = 0.f, s3 = 0.f;
#pragma unroll
  for (int r = 0; r < 16; r += 4) {
    s0 += __builtin_amdgcn_exp2f(acc[r + 0] - mn);
    s1 += __builtin_amdgcn_exp2f(acc[r + 1] - mn);
    s2 += __builtin_amdgcn_exp2f(acc[r + 2] - mn);
    s3 += __builtin_amdgcn_exp2f(acc[r + 3] - mn);
  }
  l = l * __builtin_amdgcn_exp2f(m - mn) + ((s0 + s1) + (s2 + s3));
  m = mn;
}

// ---------- pass 2: fused fp8 MFMA GEMM + online logsumexp ----------
// acc = mfma_scale_32x32x64(A=Zj_frag, B=Zi_frag, unit scales) -> D[j][i],
// col(lane&31)=i. Each lane owns TWO i rows; scalar (m,l) per row.
// grid = 32 row-blocks (256 i: 4 waves x 64) x 32 j-chunks (256 cols each).
// chunk = bid&31 -> same-chunk blocks share XCD (bid%8 == chunk%8).
// 4x8KB LDS buffers, 2 tiles per barrier region, stage issued AFTER the
// barrier (write-after-read safe), setprio around the MFMA cluster.
__global__ __launch_bounds__(256, 4) void lse_kernel(
    const uint8_t* __restrict__ Zi8, const uint8_t* __restrict__ Zj8,
    float* __restrict__ plse) {
  const int bid   = blockIdx.x;
  const int chunk = bid & 31;
  const int rb    = bid >> 5;
  const int tid   = threadIdx.x;
  const int lane  = tid & 63;
  const int w     = tid >> 6;
  const int r32   = lane & 31;
  const int h     = lane >> 5;
  const int iBase = rb * 256 + w * 64;

  __shared__ __align__(16) uint8_t lds[4][8192];

  // B fragments: this lane's two i rows, all of K=256 (32B per k-quarter).
  // k-window = 32*h + byte for both A and B -> k-permutation cancels.
  v8i b0[4], b1[4];
  const uint8_t* zb = Zi8 + (size_t)(iBase + r32) * 256 + h * 32;
#pragma unroll
  for (int q = 0; q < 4; ++q) {
    union { int4 i4[2]; v8i v; } u0, u1;
    u0.i4[0] = *(const int4*)(zb + q * 64);
    u0.i4[1] = *(const int4*)(zb + q * 64 + 16);
    u1.i4[0] = *(const int4*)(zb + 32 * 256 + q * 64);
    u1.i4[1] = *(const int4*)(zb + 32 * 256 + q * 64 + 16);
    b0[q] = u0.v; b1[q] = u1.v;
  }
#pragma unroll
  for (int q = 0; q < 4; ++q) { asm("" : "+v"(b0[q])); asm("" : "+v"(b1[q])); }

  float m0 = -1e30f, l0 = 0.f, m1 = -1e30f, l1 = 0.f;

  const uint8_t* src = Zj8 + (size_t)chunk * (256 * 256);
  const int xm = (r32 & 7) << 4;

  stage8(src, &lds[0][0], tid);
  stage8(src + 8192, &lds[1][0], tid);

  for (int s = 0; s < 4; ++s) {
    __syncthreads();  // drains prev stages; all waves done reading reused bufs
    if (s < 3) {
      stage8(src + (size_t)(2 * s + 2) * 8192, &lds[(2 * s + 2) & 3][0], tid);
      stage8(src + (size_t)(2 * s + 3) * 8192, &lds[(2 * s + 3) & 3][0], tid);
    }
#pragma unroll
    for (int sub = 0; sub < 2; ++sub) {
      const uint8_t* buf = &lds[(2 * s + sub) & 3][0] + r32 * 256;
      f32x16 acc0 = {}, acc1 = {};
      __builtin_amdgcn_s_setprio(1);
#pragma unroll
      for (int q = 0; q < 4; ++q) {
        union { int4 i4[2]; v8i v; } ua;
        const int off0 = ((q * 64) | (h * 32)) ^ xm;        // swizzled read
        const int off1 = ((q * 64 + 16) | (h * 32)) ^ xm;
        ua.i4[0] = *(const int4*)(buf + off0);
        ua.i4[1] = *(const int4*)(buf + off1);
        acc0 = __builtin_amdgcn_mfma_scale_f32_32x32x64_f8f6f4(
            ua.v, b0[q], acc0, 0, 0, 0, 0x7F7F7F7F, 0, 0x7F7F7F7F);
        acc1 = __builtin_amdgcn_mfma_scale_f32_32x32x64_f8f6f4(
            ua.v, b1[q], acc1, 0, 0, 0, 0x7F7F7F7F, 0, 0x7F7F7F7F);
      }
      __builtin_amdgcn_s_setprio(0);
      lse_update(acc0, m0, l0);
      lse_update(acc1, m1, l1);
    }
  }

  // lanes l and l+32 hold the same i with complementary j-subsets: one swap
#pragma unroll
  for (int p = 0; p < 2; ++p) {
    float m = p ? m1 : m0;
    float l = p ? l1 : l0;
    const float mo = __shfl_xor(m, 32);
    const float lo = __shfl_xor(l, 32);
    const float mn = fmaxf(m, mo);
    l = l * __builtin_amdgcn_exp2f(m - mn) + lo * __builtin_amdgcn_exp2f(mo - mn);
    if (h == 0) {
      const int i = iBase + p * 32 + r32;
      // log2-domain partial lse, [i][chunk] layout for coalesced finalize
      plse[(size_t)i * 32 + chunk] = mn + __builtin_amdgcn_logf(l);
    }
  }
}

// ---------- pass 3a: per-row combine of 32 chunk lse's + block partials ----
__global__ __launch_bounds__(256) void finalize1_kernel(
    const float* __restrict__ plse, const float* __restrict__ pos,
    float2* __restrict__ bpart) {
  const int tid = threadIdx.x;
  const int row = blockIdx.x * 256 + tid;
  float v[32];
#pragma unroll
  for (int c = 0; c < 8; ++c) {
    const float4 q = ((const float4*)(plse + (size_t)row * 32))[c];
    v[c * 4 + 0] = q.x; v[c * 4 + 1] = q.y; v[c * 4 + 2] = q.z; v[c * 4 + 3] = q.w;
  }
  float M = v[0];
#pragma unroll
  for (int c = 1; c < 32; ++c) M = fmaxf(M, v[c]);
  float S = 0.0f;
#pragma unroll
  for (int c = 0; c < 32; ++c) S += __builtin_amdgcn_exp2f(v[c] - M);
  const float lse = LN2F * (M + __builtin_amdgcn_logf(S));  // natural-log lse
  const float pv  = pos[row];
  float lsum = lse - 1000.0f * pv;
  float psum = pv;
#pragma unroll
  for (int msk = 1; msk < 64; msk <<= 1) {
    lsum += __shfl_xor(lsum, msk);
    psum += __shfl_xor(psum, msk);
  }
  __shared__ float sl[4], sp[4];
  const int w = tid >> 6, lane = tid & 63;
  if (lane == 0) { sl[w] = lsum; sp[w] = psum; }
  __syncthreads();
  if (tid == 0) {
    bpart[blockIdx.x] = make_float2(sl[0] + sl[1] + sl[2] + sl[3],
                                    sp[0] + sp[1] + sp[2] + sp[3]);
  }
}

// ---------- pass 3b: reduce 32 block partials to 2 scalars ----------
__global__ __launch_bounds__(64) void finalize2_kernel(
    const float2* __restrict__ bpart, float* __restrict__ out) {
  const int tid = threadIdx.x;
  float L = 0.0f, P = 0.0f;
  if (tid < 32) { const float2 v = bpart[tid]; L = v.x; P = v.y; }
#pragma unroll
  for (int msk = 1; msk < 64; msk <<= 1) {
    L += __shfl_xor(L, msk);
    P += __shfl_xor(P, msk);
  }
  if (tid == 0) {
    out[0] = L / (float)BATCH;  // loss
    out[1] = P;                 // sum(positives)
  }
}

extern "C" void kernel_launch(void* const* d_in, const int* in_sizes, int n_in,
                              void* d_out, int out_size, void* d_ws, size_t ws_size,
                              hipStream_t stream) {
  const float* p1 = (const float*)d_in[0];
  const float* p2 = (const float*)d_in[1];
  float* out = (float*)d_out;
  uint8_t* ws = (uint8_t*)d_ws;

  uint8_t* Zi8    = ws;                                                      // 2 MB
  uint8_t* Zj8    = ws + (size_t)2 * 1024 * 1024;                            // 2 MB
  float* pos      = (float*)(ws + (size_t)4 * 1024 * 1024);                  // 32 KB
  float2* bpart   = (float2*)(ws + (size_t)4 * 1024 * 1024 + 32 * 1024);     // 256 B
  float* plse     = (float*)(ws + (size_t)4 * 1024 * 1024 + 64 * 1024);      // 1 MB

  prep_kernel<<<dim3(2048), dim3(256), 0, stream>>>(p1, p2, Zi8, Zj8, pos);
  lse_kernel<<<dim3(1024), dim3(256), 0, stream>>>(Zi8, Zj8, plse);
  finalize1_kernel<<<dim3(32), dim3(256), 0, stream>>>(plse, pos, bpart);
  finalize2_kernel<<<dim3(1), dim3(64), 0, stream>>>(bpart, out);
}

// Round 6
// 40.402 us; speedup vs baseline: 2.3527x; 2.3527x over previous
//
#include <hip/hip_runtime.h>
#include <hip/hip_fp8.h>
#include <stdint.h>
#include <stddef.h>

#define BATCH 8192
#define DIM   256

#define LN2F 0.6931471805599453f
// operand quantization scales; product = 1000*log2(e) = 1442.6950408889634
// so MFMA accs are directly exp2-domain scores (no dequant in hot loop).
#define SCALE_ZJ 16.0f                 // A side (staged)
#define SCALE_ZI 90.16844005556021f    // B side (regs)

typedef int   v8i    __attribute__((ext_vector_type(8)));   // 32B fp8 frag (8 VGPR)
typedef float f32x16 __attribute__((ext_vector_type(16)));  // 32x32 MFMA acc

// ---------- helpers ----------
static __device__ __forceinline__ uint8_t f2fp8(float f) {
  __hip_fp8_e4m3 q(f);                       // OCP e4m3fn, RNE+sat
  return *reinterpret_cast<uint8_t*>(&q);
}

// stage one 32-row x 256B fp8 tile (8 KB): linear LDS dest, source pre-swizzled
// with byte ^= ((row&7)<<4) so the ds_read_b128 fragment reads spread banks
// (rule 21: same involution on source and read, LDS dest stays linear).
static __device__ __forceinline__ void stage8(const uint8_t* __restrict__ src,
                                              uint8_t* dst, int tid) {
  const int lane = tid & 63;
  const int w    = tid >> 6;
#pragma unroll
  for (int c = 0; c < 2; ++c) {
    const int L  = (c * 4 + w) * 1024 + lane * 16;   // linear byte in tile
    const int Ls = L ^ (((L >> 8) & 7) << 4);        // swizzled source byte
    __builtin_amdgcn_global_load_lds(
        (const __attribute__((address_space(1))) void*)(src + Ls),
        (__attribute__((address_space(3))) void*)(dst + (c * 4 + w) * 1024),
        16, 0, 0);
  }
}

// ---------- pass 1: normalize, exact fp32 positives, fp8 quantize ----------
__global__ __launch_bounds__(256) void prep_kernel(
    const float* __restrict__ p1, const float* __restrict__ p2,
    uint8_t* __restrict__ Zi8, uint8_t* __restrict__ Zj8,
    float* __restrict__ pos) {
  const int lane = threadIdx.x & 63;
  const int w    = threadIdx.x >> 6;
  const int row  = blockIdx.x * 4 + w;   // one wave per row

  const float4 x1 = ((const float4*)p1)[row * 64 + lane];
  const float4 x2 = ((const float4*)p2)[row * 64 + lane];
  float ss1 = x1.x * x1.x + x1.y * x1.y + x1.z * x1.z + x1.w * x1.w;
  float ss2 = x2.x * x2.x + x2.y * x2.y + x2.z * x2.z + x2.w * x2.w;
  float d   = x1.x * x2.x + x1.y * x2.y + x1.z * x2.z + x1.w * x2.w;
#pragma unroll
  for (int m = 1; m < 64; m <<= 1) {
    ss1 += __shfl_xor(ss1, m);
    ss2 += __shfl_xor(ss2, m);
    d   += __shfl_xor(d, m);
  }
  const float n1 = fmaxf(sqrtf(ss1), 1e-12f);
  const float n2 = fmaxf(sqrtf(ss2), 1e-12f);
  if (lane == 0) pos[row] = d / (n1 * n2);          // exact fp32 diagonal

  const float sI = SCALE_ZI / n1;
  const float sJ = SCALE_ZJ / n2;
  uchar4 u1, u2;
  u1.x = f2fp8(x1.x * sI); u1.y = f2fp8(x1.y * sI);
  u1.z = f2fp8(x1.z * sI); u1.w = f2fp8(x1.w * sI);
  u2.x = f2fp8(x2.x * sJ); u2.y = f2fp8(x2.y * sJ);
  u2.z = f2fp8(x2.z * sJ); u2.w = f2fp8(x2.w * sJ);
  ((uchar4*)Zi8)[row * 64 + lane] = u1;
  ((uchar4*)Zj8)[row * 64 + lane] = u2;
}

// ---------- online lse update for one 16-score acc block (lean temps) ------
static __device__ __forceinline__ void lse_update(const f32x16& acc,
                                                  float& m, float& l) {
  // nested fmax -> v_max3-fusable tree, minimal live temps
  float t0 = fmaxf(fmaxf(acc[0],  acc[1]),  acc[2]);
  float t1 = fmaxf(fmaxf(acc[3],  acc[4]),  acc[5]);
  float t2 = fmaxf(fmaxf(acc[6],  acc[7]),  acc[8]);
  float t3 = fmaxf(fmaxf(acc[9],  acc[10]), acc[11]);
  t0 = fmaxf(fmaxf(t0, t1), fmaxf(fmaxf(acc[12], acc[13]), acc[14]));
  t2 = fmaxf(fmaxf(t2, t3), acc[15]);
  const float mn = fmaxf(m, fmaxf(t0, t2));
  float s0 = 0.f, s1 = 0.f;
#pragma unroll
  for (int r = 0; r < 16; r += 2) {
    s0 += __builtin_amdgcn_exp2f(acc[r + 0] - mn);
    s1 += __builtin_amdgcn_exp2f(acc[r + 1] - mn);
  }
  l = l * __builtin_amdgcn_exp2f(m - mn) + (s0 + s1);
  m = mn;
}

// ---------- pass 2: fused fp8 MFMA GEMM + online logsumexp ----------
// acc = mfma_scale_32x32x64(A=Zj_frag, B=Zi_frag, unit scales) -> D[j][i],
// col(lane&31)=i. Each lane owns TWO i rows; scalar (m,l) per row.
// grid = 32 row-blocks (256 i: 4 waves x 64) x 32 j-chunks (256 cols each).
// chunk = bid&31 -> same-chunk blocks share XCD (bid%8 == chunk%8).
// 4x8KB LDS buffers, 2 tiles per barrier region, stages issued after the
// barrier (write-after-read safe), setprio around the MFMA cluster.
// launch_bounds(256,3): 168-VGPR cap fits ~140-reg wave state WITHOUT spills
// (R5 post-mortem: the ",4" 128-cap spilled accs -> 300MB scratch traffic).
__global__ __launch_bounds__(256, 3) void lse_kernel(
    const uint8_t* __restrict__ Zi8, const uint8_t* __restrict__ Zj8,
    float* __restrict__ plse) {
  const int bid   = blockIdx.x;
  const int chunk = bid & 31;
  const int rb    = bid >> 5;
  const int tid   = threadIdx.x;
  const int lane  = tid & 63;
  const int w     = tid >> 6;
  const int r32   = lane & 31;
  const int h     = lane >> 5;
  const int iBase = rb * 256 + w * 64;

  __shared__ __align__(16) uint8_t lds[4][8192];

  // B fragments: this lane's two i rows, all of K=256 (32B per k-quarter).
  // k-window = 32*h + byte for both A and B -> k-permutation cancels.
  v8i b0[4], b1[4];
  const uint8_t* zb = Zi8 + (size_t)(iBase + r32) * 256 + h * 32;
#pragma unroll
  for (int q = 0; q < 4; ++q) {
    union { int4 i4[2]; v8i v; } u0, u1;
    u0.i4[0] = *(const int4*)(zb + q * 64);
    u0.i4[1] = *(const int4*)(zb + q * 64 + 16);
    u1.i4[0] = *(const int4*)(zb + 32 * 256 + q * 64);
    u1.i4[1] = *(const int4*)(zb + 32 * 256 + q * 64 + 16);
    b0[q] = u0.v; b1[q] = u1.v;
  }
#pragma unroll
  for (int q = 0; q < 4; ++q) { asm("" : "+v"(b0[q])); asm("" : "+v"(b1[q])); }

  float m0 = -1e30f, l0 = 0.f, m1 = -1e30f, l1 = 0.f;

  const uint8_t* src = Zj8 + (size_t)chunk * (256 * 256);
  const int xm = (r32 & 7) << 4;

  stage8(src, &lds[0][0], tid);
  stage8(src + 8192, &lds[1][0], tid);

  for (int s = 0; s < 4; ++s) {
    __syncthreads();  // drains in-flight stages; reused bufs fully consumed
    if (s < 3) {
      stage8(src + (size_t)(2 * s + 2) * 8192, &lds[(2 * s + 2) & 3][0], tid);
      stage8(src + (size_t)(2 * s + 3) * 8192, &lds[(2 * s + 3) & 3][0], tid);
    }
#pragma unroll
    for (int sub = 0; sub < 2; ++sub) {
      const uint8_t* buf = &lds[(2 * s + sub) & 3][0] + r32 * 256;
      f32x16 acc0 = {}, acc1 = {};
      __builtin_amdgcn_s_setprio(1);
#pragma unroll
      for (int q = 0; q < 4; ++q) {
        union { int4 i4[2]; v8i v; } ua;
        const int off0 = ((q * 64) | (h * 32)) ^ xm;        // swizzled read
        const int off1 = ((q * 64 + 16) | (h * 32)) ^ xm;
        ua.i4[0] = *(const int4*)(buf + off0);
        ua.i4[1] = *(const int4*)(buf + off1);
        acc0 = __builtin_amdgcn_mfma_scale_f32_32x32x64_f8f6f4(
            ua.v, b0[q], acc0, 0, 0, 0, 0x7F7F7F7F, 0, 0x7F7F7F7F);
        acc1 = __builtin_amdgcn_mfma_scale_f32_32x32x64_f8f6f4(
            ua.v, b1[q], acc1, 0, 0, 0, 0x7F7F7F7F, 0, 0x7F7F7F7F);
      }
      __builtin_amdgcn_s_setprio(0);
      lse_update(acc0, m0, l0);
      lse_update(acc1, m1, l1);
    }
  }

  // lanes l and l+32 hold the same i with complementary j-subsets: one swap
#pragma unroll
  for (int p = 0; p < 2; ++p) {
    float m = p ? m1 : m0;
    float l = p ? l1 : l0;
    const float mo = __shfl_xor(m, 32);
    const float lo = __shfl_xor(l, 32);
    const float mn = fmaxf(m, mo);
    l = l * __builtin_amdgcn_exp2f(m - mn) + lo * __builtin_amdgcn_exp2f(mo - mn);
    if (h == 0) {
      const int i = iBase + p * 32 + r32;
      // log2-domain partial lse, [i][chunk] layout for coalesced finalize
      plse[(size_t)i * 32 + chunk] = mn + __builtin_amdgcn_logf(l);
    }
  }
}

// ---------- pass 3a: per-row combine of 32 chunk lse's + block partials ----
__global__ __launch_bounds__(256) void finalize1_kernel(
    const float* __restrict__ plse, const float* __restrict__ pos,
    float2* __restrict__ bpart) {
  const int tid = threadIdx.x;
  const int row = blockIdx.x * 256 + tid;
  float v[32];
#pragma unroll
  for (int c = 0; c < 8; ++c) {
    const float4 q = ((const float4*)(plse + (size_t)row * 32))[c];
    v[c * 4 + 0] = q.x; v[c * 4 + 1] = q.y; v[c * 4 + 2] = q.z; v[c * 4 + 3] = q.w;
  }
  float M = v[0];
#pragma unroll
  for (int c = 1; c < 32; ++c) M = fmaxf(M, v[c]);
  float S = 0.0f;
#pragma unroll
  for (int c = 0; c < 32; ++c) S += __builtin_amdgcn_exp2f(v[c] - M);
  const float lse = LN2F * (M + __builtin_amdgcn_logf(S));  // natural-log lse
  const float pv  = pos[row];
  float lsum = lse - 1000.0f * pv;
  float psum = pv;
#pragma unroll
  for (int msk = 1; msk < 64; msk <<= 1) {
    lsum += __shfl_xor(lsum, msk);
    psum += __shfl_xor(psum, msk);
  }
  __shared__ float sl[4], sp[4];
  const int w = tid >> 6, lane = tid & 63;
  if (lane == 0) { sl[w] = lsum; sp[w] = psum; }
  __syncthreads();
  if (tid == 0) {
    bpart[blockIdx.x] = make_float2(sl[0] + sl[1] + sl[2] + sl[3],
                                    sp[0] + sp[1] + sp[2] + sp[3]);
  }
}

// ---------- pass 3b: reduce 32 block partials to 2 scalars ----------
__global__ __launch_bounds__(64) void finalize2_kernel(
    const float2* __restrict__ bpart, float* __restrict__ out) {
  const int tid = threadIdx.x;
  float L = 0.0f, P = 0.0f;
  if (tid < 32) { const float2 v = bpart[tid]; L = v.x; P = v.y; }
#pragma unroll
  for (int msk = 1; msk < 64; msk <<= 1) {
    L += __shfl_xor(L, msk);
    P += __shfl_xor(P, msk);
  }
  if (tid == 0) {
    out[0] = L / (float)BATCH;  // loss
    out[1] = P;                 // sum(positives)
  }
}

extern "C" void kernel_launch(void* const* d_in, const int* in_sizes, int n_in,
                              void* d_out, int out_size, void* d_ws, size_t ws_size,
                              hipStream_t stream) {
  const float* p1 = (const float*)d_in[0];
  const float* p2 = (const float*)d_in[1];
  float* out = (float*)d_out;
  uint8_t* ws = (uint8_t*)d_ws;

  uint8_t* Zi8    = ws;                                                      // 2 MB
  uint8_t* Zj8    = ws + (size_t)2 * 1024 * 1024;                            // 2 MB
  float* pos      = (float*)(ws + (size_t)4 * 1024 * 1024);                  // 32 KB
  float2* bpart   = (float2*)(ws + (size_t)4 * 1024 * 1024 + 32 * 1024);     // 256 B
  float* plse     = (float*)(ws + (size_t)4 * 1024 * 1024 + 64 * 1024);      // 1 MB

  prep_kernel<<<dim3(2048), dim3(256), 0, stream>>>(p1, p2, Zi8, Zj8, pos);
  lse_kernel<<<dim3(1024), dim3(256), 0, stream>>>(Zi8, Zj8, plse);
  finalize1_kernel<<<dim3(32), dim3(256), 0, stream>>>(plse, pos, bpart);
  finalize2_kernel<<<dim3(1), dim3(64), 0, stream>>>(bpart, out);
}